// Round 1
// baseline (220.082 us; speedup 1.0000x reference)
//
#include <hip/hip_runtime.h>
#include <math.h>

#define VOCAB 32000
#define PADDING_IDX 0

// Loss collapses to (per row i with t = target[i] != 0):
//   C - 0.9*x[i,t] - s*(S_i - x[i,0] - x[i,t])
// where s = 0.1/(VOCAB-2), C = 0.9*log(0.9) + 0.1*log(s), S_i = row sum.
// Rows with t == PADDING_IDX contribute 0.

__global__ __launch_bounds__(256) void LabelSmoothing_62792421868006_kernel(
    const float* __restrict__ x,
    const int* __restrict__ target,
    float* __restrict__ out)
{
    const int row = blockIdx.x;
    const float* __restrict__ xr = x + (size_t)row * VOCAB;
    const int t = target[row];

    // Row sum via float4 loads: VOCAB/4 = 8000 float4 per row.
    float s = 0.0f;
    const float4* __restrict__ xr4 = (const float4*)xr;
    for (int j = threadIdx.x; j < VOCAB / 4; j += 256) {
        float4 v = xr4[j];
        s += (v.x + v.y) + (v.z + v.w);
    }

    // Wave-64 shuffle reduce.
    #pragma unroll
    for (int off = 32; off > 0; off >>= 1)
        s += __shfl_down(s, off, 64);

    __shared__ float ws[4];
    const int lane = threadIdx.x & 63;
    const int wid  = threadIdx.x >> 6;
    if (lane == 0) ws[wid] = s;
    __syncthreads();

    if (threadIdx.x == 0) {
        if (t != PADDING_IDX) {
            const float S = (ws[0] + ws[1]) + (ws[2] + ws[3]);
            const float SMOOTH = 0.1f / (float)(VOCAB - 2);
            const float CONF = 0.9f;
            const float C = CONF * logf(CONF) + 0.1f * logf(SMOOTH);
            const float x0 = xr[0];
            const float xt = xr[t];
            const float contrib = C - CONF * xt - SMOOTH * (S - x0 - xt);
            atomicAdd(out, contrib);
        }
    }
}

extern "C" void kernel_launch(void* const* d_in, const int* in_sizes, int n_in,
                              void* d_out, int out_size, void* d_ws, size_t ws_size,
                              hipStream_t stream) {
    const float* x      = (const float*)d_in[0];
    const int*   target = (const int*)d_in[1];
    float* out = (float*)d_out;

    const int N = in_sizes[1];  // 8192 rows (target has one entry per row)

    // Harness poisons d_out once and never re-poisons between replays:
    // zero it ourselves every call (async memset is graph-capture safe).
    hipMemsetAsync(out, 0, sizeof(float) * out_size, stream);

    LabelSmoothing_62792421868006_kernel<<<N, 256, 0, stream>>>(x, target, out);
}

// Round 2
// 163.409 us; speedup vs baseline: 1.3468x; 1.3468x over previous
//
#include <hip/hip_runtime.h>
#include <math.h>

#define VOCAB 32000
#define PADDING_IDX 0

typedef float f32x4 __attribute__((ext_vector_type(4)));

// Loss collapses to (per row i with t = target[i] != 0):
//   C - 0.9*x[i,t] - s*(S_i - x[i,0] - x[i,t])
// where s = 0.1/(VOCAB-2), C = 0.9*log(0.9) + 0.1*log(s), S_i = row sum.
// Rows with t == PADDING_IDX contribute 0.
//
// Stage 1: one block per row -> per-row contrib into d_ws (no atomics).
// Stage 2: one block reduces the 8192 partials into d_out[0].

__global__ __launch_bounds__(256) void ls_row_kernel(
    const float* __restrict__ x,
    const int* __restrict__ target,
    float* __restrict__ ws)
{
    const int row = blockIdx.x;
    const float* __restrict__ xr = x + (size_t)row * VOCAB;
    const int t = target[row];

    const f32x4* __restrict__ xr4 = (const f32x4*)xr;

    // VOCAB/4 = 8000 float4 per row. Unroll x2 with independent accumulators.
    // 8000 = 15*512 + 320; threads 0..63 of the remainder chunk do one extra.
    float sa = 0.0f, sb = 0.0f;
    int j = threadIdx.x;
    #pragma unroll 4
    for (; j + 256 < VOCAB / 4; j += 512) {
        f32x4 a = __builtin_nontemporal_load(xr4 + j);
        f32x4 b = __builtin_nontemporal_load(xr4 + j + 256);
        sa += (a[0] + a[1]) + (a[2] + a[3]);
        sb += (b[0] + b[1]) + (b[2] + b[3]);
    }
    if (j < VOCAB / 4) {
        f32x4 a = __builtin_nontemporal_load(xr4 + j);
        sa += (a[0] + a[1]) + (a[2] + a[3]);
    }
    float s = sa + sb;

    // Wave-64 shuffle reduce.
    #pragma unroll
    for (int off = 32; off > 0; off >>= 1)
        s += __shfl_down(s, off, 64);

    __shared__ float wsum[4];
    const int lane = threadIdx.x & 63;
    const int wid  = threadIdx.x >> 6;
    if (lane == 0) wsum[wid] = s;
    __syncthreads();

    if (threadIdx.x == 0) {
        float contrib = 0.0f;
        if (t != PADDING_IDX) {
            const float S = (wsum[0] + wsum[1]) + (wsum[2] + wsum[3]);
            const float SMOOTH = 0.1f / (float)(VOCAB - 2);
            const float CONF = 0.9f;
            const float C = CONF * logf(CONF) + 0.1f * logf(SMOOTH);
            const float x0 = xr[0];
            const float xt = xr[t];
            contrib = C - CONF * xt - SMOOTH * (S - x0 - xt);
        }
        ws[row] = contrib;
    }
}

__global__ __launch_bounds__(256) void ls_final_kernel(
    const float* __restrict__ ws,
    float* __restrict__ out,
    int n)
{
    float s = 0.0f;
    for (int j = threadIdx.x; j < n; j += 256)
        s += ws[j];

    #pragma unroll
    for (int off = 32; off > 0; off >>= 1)
        s += __shfl_down(s, off, 64);

    __shared__ float wsum[4];
    const int lane = threadIdx.x & 63;
    const int wid  = threadIdx.x >> 6;
    if (lane == 0) wsum[wid] = s;
    __syncthreads();

    if (threadIdx.x == 0)
        out[0] = (wsum[0] + wsum[1]) + (wsum[2] + wsum[3]);
}

extern "C" void kernel_launch(void* const* d_in, const int* in_sizes, int n_in,
                              void* d_out, int out_size, void* d_ws, size_t ws_size,
                              hipStream_t stream) {
    const float* x      = (const float*)d_in[0];
    const int*   target = (const int*)d_in[1];
    float* out = (float*)d_out;
    float* ws  = (float*)d_ws;

    const int N = in_sizes[1];  // 8192 rows

    ls_row_kernel<<<N, 256, 0, stream>>>(x, target, ws);
    ls_final_kernel<<<1, 256, 0, stream>>>(ws, out, N);
}